// Round 5
// baseline (631.249 us; speedup 1.0000x reference)
//
#include <hip/hip_runtime.h>
#include <hip/hip_cooperative_groups.h>
#include <math.h>

namespace cg = cooperative_groups;

#define B_ 64
#define N_ 512
#define R_ (B_*N_)                  // 32768 rows
#define INV_S 0.9995003746877732f   // 1/sqrt(1+1e-3)

struct FusedArgs {
  const float* xx;
  const float* emb1; const float* emb2; const float* emb3;
  const float* A0;  const float* b0;
  const float* Ar;  const float* br;
  const float* bng; const float* bnb;
  const float* dW0; const float* db0;
  const float* dW1; const float* db1;
  const float* dbg; const float* dbb;
  const float* W2;  const float* b2;
  float* xA; float* xB; float* partial;
  float* out;
};

// ---------------------------------------------------------------------------
// One cooperative kernel, 256 blocks x 256 threads. 256 blocks <= 256 CUs at
// >=1 block/CU guarantees the cooperative co-residency check passes (round 4
// asked for 512 = exactly 2/CU with 61KB LDS; zero margin -> rejected).
// Block (b = bid>>2, q4 = bid&3) owns j-chunks {2*q4, 2*q4+1} of batch b.
//  Per layer L=0..4:
//   - stage batch coords (512 x float4) + A lo/hi (zero-padded to K=64) ONCE
//   - for sub=0,1: stage x tile (64x64, stride 68) + mask, compute S/T
//     (4 waves x 128-i ranges), 64x64 GEMM tile (thread = 4 rows x 4 outs x
//     2 mats, ds_read_b128), alast/bias/mask/bn/tanh epilogue -> ping-pong
//   - grid.sync()
//  Dense0: block bid = k-chunk of 128 (256*128 = 32768 = full K) -> partial.
//  Head (blocks 0..63): reduce 256 partials -> bn+sigmoid -> 128x128 GEMV
//  -> bn+sigmoid -> @W2 + b2 -> out (B,4).
// ---------------------------------------------------------------------------
__global__ __launch_bounds__(256, 4) void gnn_fused(FusedArgs a)
{
  __shared__ union {
    struct {
      float4 cl[512];
      float alo[64*64];
      float ahi[64*64];
      float xl[64*68];
      float spart[256], tpart[256];
    } lay;
    struct {
      float xt[64*68];
      float wt[64*128];
    } den;
    struct {
      float sred[256]; float h[128]; float red0[128]; float red1[128];
    } head;
  } u;
  __shared__ float scl[64], tcl[64], ml[64];

  cg::grid_group grid = cg::this_grid();
  int tid = threadIdx.x;
  int bid = blockIdx.x;
  int b = bid >> 2, q4 = bid & 3;
  int rbase = b*N_;

  // ======================== GNN layers ========================
  for (int L = 0; L < 5; L++){
    const float* A    = (L==0) ? a.A0 : (a.Ar + (size_t)(L-1)*129*64);
    const float* bias = (L==0) ? a.b0 : (a.br + (L-1)*64);
    const float* gam  = a.bng + L*64;
    const float* bet  = a.bnb + L*64;
    int K = (L==0) ? 33 : 64;
    const float* xin  = (L&1) ? a.xA : a.xB;   // valid for L>=1
    float* xout       = (L&1) ? a.xB : a.xA;

    // ---- stage coords for all 512 rows of this batch (once per layer) ----
    if (L == 0){
      for (int i = tid; i < 512; i += 256){
        const float* row = a.xx + (size_t)(rbase+i)*30;
        u.lay.cl[i] = make_float4(row[25], row[26], 0.f, 0.f);
      }
    } else {
      for (int i = tid; i < 512; i += 256)
        u.lay.cl[i] = *(const float4*)&xin[(size_t)(rbase+i)*64 + 60];
    }

    // ---- stage A lo/hi, zero-pad rows K..63 (once per layer) ----
    for (int idx = tid; idx < 4096; idx += 256){
      int f = idx >> 6;
      u.lay.alo[idx] = (f < K) ? A[idx] : 0.f;
      u.lay.ahi[idx] = (f < K) ? A[(size_t)K*64 + idx] : 0.f;
    }

    for (int sub = 0; sub < 2; sub++){
      int jloc = (q4*2 + sub)*64;
      __syncthreads();   // cl/A ready (sub=0); xl reuse safe (sub=1)

      // ---- stage x tile (64 rows x 64 cols, stride 68) + mask ----
      if (L == 0){
        if (tid < 64){
          int r = rbase + jloc + tid;
          const float* row = a.xx + (size_t)r*30;
          float v[30];
#pragma unroll
          for (int i=0;i<30;i++) v[i] = row[i];
          int i1 = (int)fabsf(v[27]);
          int i2 = (int)fabsf(v[28]);
          int i3 = (int)fabsf(v[29]);
          float* o = &u.lay.xl[tid*68];
          o[0]=a.emb1[i1*2+0]; o[1]=a.emb1[i1*2+1];
          o[2]=a.emb2[i2*2+0]; o[3]=a.emb2[i2*2+1];
          o[4]=a.emb3[i3*2+0]; o[5]=a.emb3[i3*2+1];
#pragma unroll
          for (int i=0;i<27;i++) o[6+i] = v[i];
#pragma unroll
          for (int i=33;i<64;i++) o[i] = 0.f;
          ml[tid] = v[0];
        }
      } else {
        for (int idx = tid; idx < 1024; idx += 256){
          int jj = idx >> 4, fq = idx & 15;
          *(float4*)&u.lay.xl[jj*68 + fq*4] =
              *(const float4*)&xin[(size_t)(rbase+jloc+jj)*64 + fq*4];
        }
        if (tid < 64) ml[tid] = a.xx[(size_t)(rbase+jloc+tid)*30];
      }
      __syncthreads();

      // ---- S,T: wave q sums i in [q*128, q*128+128) for j = tid&63 ----
      {
        int jj = tid & 63, q = tid >> 6;
        float4 cj = u.lay.cl[jloc + jj];
        float Ss = 0.f, Ts = 0.f;
        int base = q*128;
#pragma unroll 8
        for (int i=0;i<128;i++){
          float4 ci = u.lay.cl[base+i];
          float d0 = cj.x-ci.x, d1 = cj.y-ci.y, d2 = cj.z-ci.z, d3 = cj.w-ci.w;
          float dist = d0*d0 + d1*d1 + d2*d2 + d3*d3;
          float w = __expf(-10.f*dist);
          Ss += w;
          Ts += dist*w;
        }
        u.lay.spart[tid] = Ss;
        u.lay.tpart[tid] = Ts;
      }
      __syncthreads();
      if (tid < 64){
        float S = u.lay.spart[tid] + u.lay.spart[tid+64]
                + u.lay.spart[tid+128] + u.lay.spart[tid+192];
        float T = u.lay.tpart[tid] + u.lay.tpart[tid+64]
                + u.lay.tpart[tid+128] + u.lay.tpart[tid+192];
        float m = ml[tid];
        scl[tid] = m*S - 1.f;
        tcl[tid] = m*T;
      }
      __syncthreads();

      // ---- GEMM tile: thread = 4 rows x 4 outs, two matrices ----
      int o0 = (tid & 15)*4, r0 = (tid >> 4)*4;
      float4 acc1[4], acc2[4];
#pragma unroll
      for (int rr=0;rr<4;rr++){
        acc1[rr] = make_float4(0.f,0.f,0.f,0.f);
        acc2[rr] = make_float4(0.f,0.f,0.f,0.f);
      }
#pragma unroll 1
      for (int kc = 0; kc < 64; kc += 4){
        float4 a1[4], a2[4], xv[4];
#pragma unroll
        for (int uu=0;uu<4;uu++){
          a1[uu] = *(const float4*)&u.lay.alo[(kc+uu)*64 + o0];
          a2[uu] = *(const float4*)&u.lay.ahi[(kc+uu)*64 + o0];
        }
#pragma unroll
        for (int rr=0;rr<4;rr++)
          xv[rr] = *(const float4*)&u.lay.xl[(r0+rr)*68 + kc];
#pragma unroll
        for (int uu=0;uu<4;uu++){
#pragma unroll
          for (int rr=0;rr<4;rr++){
            float xu = ((const float*)&xv[rr])[uu];
            acc1[rr].x = fmaf(xu, a1[uu].x, acc1[rr].x);
            acc1[rr].y = fmaf(xu, a1[uu].y, acc1[rr].y);
            acc1[rr].z = fmaf(xu, a1[uu].z, acc1[rr].z);
            acc1[rr].w = fmaf(xu, a1[uu].w, acc1[rr].w);
            acc2[rr].x = fmaf(xu, a2[uu].x, acc2[rr].x);
            acc2[rr].y = fmaf(xu, a2[uu].y, acc2[rr].y);
            acc2[rr].z = fmaf(xu, a2[uu].z, acc2[rr].z);
            acc2[rr].w = fmaf(xu, a2[uu].w, acc2[rr].w);
          }
        }
      }

      float4 alast = *(const float4*)&A[(size_t)2*K*64 + o0];
      float4 bo = *(const float4*)&bias[o0];
      float4 go = *(const float4*)&gam[o0];
      float4 be = *(const float4*)&bet[o0];
#pragma unroll
      for (int rr=0;rr<4;rr++){
        int r = rbase + jloc + r0 + rr;
        float sc = scl[r0+rr], tc = tcl[r0+rr], m = ml[r0+rr];
        float4 v;
        v.x = (acc1[rr].x + sc*acc2[rr].x + tc*alast.x + bo.x)*m;
        v.y = (acc1[rr].y + sc*acc2[rr].y + tc*alast.y + bo.y)*m;
        v.z = (acc1[rr].z + sc*acc2[rr].z + tc*alast.z + bo.z)*m;
        v.w = (acc1[rr].w + sc*acc2[rr].w + tc*alast.w + bo.w)*m;
        float4 t;
        t.x = tanhf(go.x*(v.x*INV_S) + be.x);
        t.y = tanhf(go.y*(v.y*INV_S) + be.y);
        t.z = tanhf(go.z*(v.z*INV_S) + be.z);
        t.w = tanhf(go.w*(v.w*INV_S) + be.w);
        *(float4*)&xout[(size_t)r*64 + o0] = t;
      }
    }
    __threadfence();
    grid.sync();
  }

  // ======================== dense0 split-K partial ========================
  // x5 lives in xA (L4 wrote xA). X viewed as (64, 32768) row-major.
  {
    int k0 = bid*128;
    const float* X = a.xA;
    int og = (tid & 15)*8, rg = (tid >> 4)*4;
    float acc[4][8];
#pragma unroll
    for (int rr=0;rr<4;rr++)
#pragma unroll
      for (int uu=0;uu<8;uu++) acc[rr][uu]=0.f;
    for (int kt = 0; kt < 128; kt += 64){
      __syncthreads();
      for (int idx = tid; idx < 1024; idx += 256){
        int r = idx >> 4, kq = idx & 15;
        *(float4*)&u.den.xt[r*68 + kq*4] =
            *(const float4*)&X[(size_t)r*32768 + k0 + kt + kq*4];
      }
      {
        const float4* Wc = (const float4*)&a.dW0[(size_t)(k0+kt)*128];
        float4* wt4 = (float4*)u.den.wt;
        for (int idx = tid; idx < 2048; idx += 256) wt4[idx] = Wc[idx];
      }
      __syncthreads();
#pragma unroll 4
      for (int k=0;k<64;k++){
        float4 w0 = *(const float4*)&u.den.wt[k*128 + og];
        float4 w1 = *(const float4*)&u.den.wt[k*128 + og + 4];
        float xs[4];
#pragma unroll
        for (int rr=0;rr<4;rr++) xs[rr] = u.den.xt[(rg+rr)*68 + k];
#pragma unroll
        for (int rr=0;rr<4;rr++){
          acc[rr][0] = fmaf(xs[rr], w0.x, acc[rr][0]);
          acc[rr][1] = fmaf(xs[rr], w0.y, acc[rr][1]);
          acc[rr][2] = fmaf(xs[rr], w0.z, acc[rr][2]);
          acc[rr][3] = fmaf(xs[rr], w0.w, acc[rr][3]);
          acc[rr][4] = fmaf(xs[rr], w1.x, acc[rr][4]);
          acc[rr][5] = fmaf(xs[rr], w1.y, acc[rr][5]);
          acc[rr][6] = fmaf(xs[rr], w1.z, acc[rr][6]);
          acc[rr][7] = fmaf(xs[rr], w1.w, acc[rr][7]);
        }
      }
    }
    float* pb = a.partial + (size_t)bid*8192;
#pragma unroll
    for (int rr=0;rr<4;rr++){
      *(float4*)&pb[(rg+rr)*128 + og]     = *(float4*)&acc[rr][0];
      *(float4*)&pb[(rg+rr)*128 + og + 4] = *(float4*)&acc[rr][4];
    }
    __threadfence();
  }
  grid.sync();

  // ======================== head (blocks 0..63) ========================
  if (bid < 64){
    int bb = bid;
    int o = tid & 127, ph = tid >> 7;
    float s = 0.f;
#pragma unroll 16
    for (int p = ph*128; p < ph*128+128; p++)
      s += a.partial[(size_t)p*8192 + bb*128 + o];
    u.head.sred[tid] = s;
    __syncthreads();
    if (tid < 128){
      float sum = u.head.sred[tid] + u.head.sred[tid+128];
      float v = a.dbg[tid]*((sum + a.db0[tid])*INV_S) + a.dbb[tid];
      u.head.h[tid] = 1.f/(1.f + __expf(-v));
    }
    __syncthreads();
    if (tid < 128){
      float acc = 0.f;
#pragma unroll 8
      for (int k=0;k<128;k++) acc = fmaf(u.head.h[k], a.dW1[k*128 + tid], acc);
      float v = a.dbg[128+tid]*((acc + a.db1[tid])*INV_S) + a.dbb[128+tid];
      float h1 = 1.f/(1.f + __expf(-v));
      u.head.red0[tid] = h1 * a.W2[tid*2+0];
      u.head.red1[tid] = h1 * a.W2[tid*2+1];
    }
    __syncthreads();
    for (int st=64; st>0; st>>=1){
      if (tid < st){
        u.head.red0[tid] += u.head.red0[tid+st];
        u.head.red1[tid] += u.head.red1[tid+st];
      }
      __syncthreads();
    }
    if (tid == 0){
      a.out[bb*4+0] = u.head.red0[0] + a.b2[0];
      a.out[bb*4+1] = u.head.red1[0] + a.b2[1];
      a.out[bb*4+2] = 0.f;
      a.out[bb*4+3] = 0.f;
    }
  }
}

// ---------------------------------------------------------------------------
extern "C" void kernel_launch(void* const* d_in, const int* in_sizes, int n_in,
                              void* d_out, int out_size, void* d_ws, size_t ws_size,
                              hipStream_t stream)
{
  float* ws = (float*)d_ws;
  FusedArgs fa;
  fa.xx   = (const float*)d_in[0];
  fa.emb1 = (const float*)d_in[1];
  fa.emb2 = (const float*)d_in[2];
  fa.emb3 = (const float*)d_in[3];
  fa.A0   = (const float*)d_in[4];
  fa.b0   = (const float*)d_in[5];
  fa.Ar   = (const float*)d_in[6];
  fa.br   = (const float*)d_in[7];
  fa.bng  = (const float*)d_in[8];
  fa.bnb  = (const float*)d_in[9];
  fa.dW0  = (const float*)d_in[10];
  fa.db0  = (const float*)d_in[11];
  fa.dW1  = (const float*)d_in[12];
  fa.db1  = (const float*)d_in[13];
  fa.dbg  = (const float*)d_in[14];
  fa.dbb  = (const float*)d_in[15];
  fa.W2   = (const float*)d_in[16];
  fa.b2   = (const float*)d_in[17];
  fa.xA   = ws;                         // 32768*64
  fa.xB   = fa.xA + (size_t)R_*64;      // 32768*64
  fa.partial = fa.xB + (size_t)R_*64;   // 256*8192
  fa.out  = (float*)d_out;

  void* kargs[] = { &fa };
  hipLaunchCooperativeKernel((const void*)gnn_fused, dim3(256), dim3(256),
                             kargs, 0, stream);
}